// Round 1
// 685.619 us; speedup vs baseline: 1.0504x; 1.0504x over previous
//
#include <hip/hip_runtime.h>

#define B_ 32
#define K_ 10
#define T_ 128
#define L_ 128
#define D_ 1024
#define NT_ 32
#define S_ (K_*L_)     // 1280
#define NCH_ 10        // S chunks of 128 (gemm)
#define SCH_ 128
#define PVW_ (NCH_*2)  // pval entries per row (chunk x n-half)
#define BIGF 1e30f

// proto scatter tiling
#define PSC_ 10        // s-chunks of 128
#define PDC_ 4         // d-chunks of 256

typedef __attribute__((ext_vector_type(8))) short short8;
typedef __attribute__((ext_vector_type(4))) float f32x4;

__device__ __forceinline__ unsigned short bf16rn(float f){
  unsigned int u = __float_as_uint(f);
  u = (u + 0x7FFFu + ((u >> 16) & 1u)) >> 16;
  return (unsigned short)u;
}
__device__ __forceinline__ float bf2f(unsigned short h){
  return __uint_as_float(((unsigned int)h) << 16);
}

// ---------------- K0: zero proto accumulator + counts ----------------
__global__ __launch_bounds__(256) void k_zero(float* __restrict__ proto, int* __restrict__ cnt){
  int idx = blockIdx.x*256 + threadIdx.x;     // 1024 blocks -> 262144 float4 = B*NT*D floats
  ((float4*)proto)[idx] = make_float4(0.f,0.f,0.f,0.f);
  if(blockIdx.x == 0){
    ((int4*)cnt)[threadIdx.x] = make_int4(0,0,0,0);   // B*NT = 1024 ints
  }
}

// ---------------- K1: test_mean = mean over K ----------------
__global__ __launch_bounds__(256) void k_mean(const float* __restrict__ tr, float* __restrict__ tm){
  int idx = blockIdx.x*256 + threadIdx.x;       // over B*T*(D/4)
  int d4 = idx & 255;
  int t  = (idx >> 8) & 127;
  int b  = idx >> 15;
  const float4* p = (const float4*)tr;
  float4 a = make_float4(0.f,0.f,0.f,0.f);
  #pragma unroll
  for(int k=0;k<K_;k++){
    float4 v = p[((size_t)(b*K_+k)*T_ + t)*(D_/4) + d4];
    a.x+=v.x; a.y+=v.y; a.z+=v.z; a.w+=v.w;
  }
  const float sc = 1.f/(float)K_;
  a.x*=sc; a.y*=sc; a.z*=sc; a.w*=sc;
  ((float4*)tm)[((size_t)b*T_ + t)*(D_/4) + d4] = a;
}

// ---------------- K2: labels from one-hot targets (+ per-(b,n) counts) ----------------
__global__ __launch_bounds__(256) void k_label(const float* __restrict__ tgt, int* __restrict__ labels,
                                               int* __restrict__ cnt){
  int r = blockIdx.x*256 + threadIdx.x;         // r < B*S
  const float4* p = (const float4*)tgt + (size_t)r*8;
  int lbl = 0;
  #pragma unroll
  for(int j=0;j<8;j++){
    float4 v = p[j];
    if(v.x>0.5f) lbl=j*4+0;
    if(v.y>0.5f) lbl=j*4+1;
    if(v.z>0.5f) lbl=j*4+2;
    if(v.w>0.5f) lbl=j*4+3;
  }
  labels[r] = lbl;
  atomicAdd(&cnt[(r/S_)*NT_ + lbl], 1);
}

// ---------------- K3a: prototype partial sums, split-S scatter ----------------
// grid B*PSC_*PDC_ = 1280 blocks, 256 thr. Block = (b, s-chunk of 128, d-chunk of 256 cols).
// thread: cg = tid&63 (float4 col group), ph = tid>>6 (s-phase 0..3); 32 s-iters, batched 8.
// LDS acc[NT][256] (32KB) accumulated via ds_add; flushed with global atomicAdd into proto.
__global__ __launch_bounds__(256) void k_proto_partial(const float* __restrict__ sup,
        const int* __restrict__ labels, float* __restrict__ proto){
  __shared__ float acc[NT_][256];
  __shared__ int lbl_s[SCH_];
  int blk = blockIdx.x;
  int b  = blk / (PSC_*PDC_);
  int rem = blk % (PSC_*PDC_);
  int sc = rem / PDC_;
  int dc = rem % PDC_;
  int tid = threadIdx.x;
  int cg = tid & 63, ph = tid >> 6;

  for(int i=tid;i<NT_*256;i+=256) (&acc[0][0])[i] = 0.f;
  if(tid < SCH_) lbl_s[tid] = labels[b*S_ + sc*SCH_ + tid];
  __syncthreads();

  const float* base = sup + ((size_t)b*S_ + sc*SCH_)*D_ + dc*256 + cg*4;
  #pragma unroll 1
  for(int i0=0;i0<32;i0+=8){
    float4 v[8];
    #pragma unroll
    for(int j=0;j<8;j++){
      int sl = ph + (i0+j)*4;
      v[j] = *(const float4*)(base + (size_t)sl*D_);
    }
    #pragma unroll
    for(int j=0;j<8;j++){
      int sl = ph + (i0+j)*4;
      int l = lbl_s[sl];
      atomicAdd(&acc[l][cg*4+0], v[j].x);
      atomicAdd(&acc[l][cg*4+1], v[j].y);
      atomicAdd(&acc[l][cg*4+2], v[j].z);
      atomicAdd(&acc[l][cg*4+3], v[j].w);
    }
  }
  __syncthreads();

  float* pbase = proto + (size_t)b*NT_*D_ + dc*256;
  for(int i=tid;i<NT_*256;i+=256){
    int n = i >> 8, col = i & 255;
    atomicAdd(&pbase[(size_t)n*D_ + col], acc[n][col]);
  }
}

// ---------------- K3b: divide by counts ----------------
__global__ __launch_bounds__(256) void k_proto_div(float* __restrict__ proto, const int* __restrict__ cnt){
  int idx = blockIdx.x*256 + threadIdx.x;     // over B*NT*(D/4) = 262144
  int n = (idx >> 8) & 31;
  int b = idx >> 13;
  float inv = 1.f / ((float)cnt[b*NT_ + n] + 1e-4f);
  float4 v = ((float4*)proto)[idx];
  v.x*=inv; v.y*=inv; v.z*=inv; v.w*=inv;
  ((float4*)proto)[idx] = v;
}

// ---------------- K4: split-bf16 MFMA GEMM (-2*t.s + ||s||^2) + per-chunk argmin ----------------
// grid b*NCH_; 256 thr = 4 waves in 2x2; block tile 128(T) x 128(S), BK=32 fp32 staged as bf16 hi/lo.
// LDS frag-major: seg(mt,p) = 1KB holding the exact 64-lane x 16B fragment -> conflict-free b128.
__global__ __launch_bounds__(256) void k_gemm_argmin(const float* __restrict__ tm, const float* __restrict__ sup,
        float* __restrict__ pval, int* __restrict__ pidx){
  __shared__ __align__(16) short ldsA[16*512];   // 8 mt x 2 planes x 512 shorts (1KB segs)
  __shared__ __align__(16) short ldsB[16*512];
  __shared__ float normB[128];

  int b = blockIdx.x / NCH_;
  int ch = blockIdx.x % NCH_;
  int sbase = ch * SCH_;
  int tid = threadIdx.x;
  int wave = tid >> 6, lane = tid & 63;
  int r = tid >> 1, kh = tid & 1;               // staging: row 0..127, k-half
  int mbase = (wave >> 1)*4;                    // wave's first mtile
  int nbase = (wave & 1)*4;                     // wave's first ntile

  const float* pa_base = tm  + ((size_t)b*T_ + r)*D_ + kh*16;
  const float* pb_base = sup + ((size_t)b*S_ + sbase + r)*D_ + kh*16;

  f32x4 acc[4][4];
  #pragma unroll
  for(int i=0;i<4;i++)
    #pragma unroll
    for(int j=0;j<4;j++) acc[i][j] = (f32x4){0.f,0.f,0.f,0.f};

  float nrm = 0.f;
  float4 a_reg[4], b_reg[4];
  #pragma unroll
  for(int it=0;it<4;it++){
    a_reg[it] = *(const float4*)(pa_base + it*4);
    b_reg[it] = *(const float4*)(pb_base + it*4);
  }

  for(int st=0; st<32; st++){
    __syncthreads();                            // LDS free (prev compute done)
    // convert + store hi/lo planes, accumulate sup row sumsq from fp32
    #pragma unroll
    for(int it=0;it<4;it++){
      float4 v = a_reg[it];
      int basei = ((r>>4)*2)*512 + ((kh*2+(it>>1))*16 + (r&15))*8 + (it&1)*4;
      unsigned short hx=bf16rn(v.x), hy=bf16rn(v.y), hz=bf16rn(v.z), hw=bf16rn(v.w);
      *(uint2*)&ldsA[basei] = make_uint2((unsigned)hx|((unsigned)hy<<16),(unsigned)hz|((unsigned)hw<<16));
      unsigned short lx=bf16rn(v.x-bf2f(hx)), ly=bf16rn(v.y-bf2f(hy)), lz=bf16rn(v.z-bf2f(hz)), lw=bf16rn(v.w-bf2f(hw));
      *(uint2*)&ldsA[basei + 512] = make_uint2((unsigned)lx|((unsigned)ly<<16),(unsigned)lz|((unsigned)lw<<16));

      float4 w = b_reg[it];
      nrm += w.x*w.x + w.y*w.y + w.z*w.z + w.w*w.w;
      unsigned short qx=bf16rn(w.x), qy=bf16rn(w.y), qz=bf16rn(w.z), qw=bf16rn(w.w);
      *(uint2*)&ldsB[basei] = make_uint2((unsigned)qx|((unsigned)qy<<16),(unsigned)qz|((unsigned)qw<<16));
      unsigned short ux=bf16rn(w.x-bf2f(qx)), uy=bf16rn(w.y-bf2f(qy)), uz=bf16rn(w.z-bf2f(qz)), uw=bf16rn(w.w-bf2f(qw));
      *(uint2*)&ldsB[basei + 512] = make_uint2((unsigned)ux|((unsigned)uy<<16),(unsigned)uz|((unsigned)uw<<16));
    }
    __syncthreads();
    if(st < 31){
      #pragma unroll
      for(int it=0;it<4;it++){
        a_reg[it] = *(const float4*)(pa_base + (st+1)*32 + it*4);
        b_reg[it] = *(const float4*)(pb_base + (st+1)*32 + it*4);
      }
    }
    short8 ah[4], al[4], bh[4], bl[4];
    #pragma unroll
    for(int i=0;i<4;i++){
      ah[i] = *(const short8*)&ldsA[((mbase+i)*2+0)*512 + lane*8];
      al[i] = *(const short8*)&ldsA[((mbase+i)*2+1)*512 + lane*8];
      bh[i] = *(const short8*)&ldsB[((nbase+i)*2+0)*512 + lane*8];
      bl[i] = *(const short8*)&ldsB[((nbase+i)*2+1)*512 + lane*8];
    }
    #pragma unroll
    for(int i=0;i<4;i++)
      #pragma unroll
      for(int j=0;j<4;j++){
        acc[i][j] = __builtin_amdgcn_mfma_f32_16x16x32_bf16(ah[i], bh[j], acc[i][j], 0,0,0);
        acc[i][j] = __builtin_amdgcn_mfma_f32_16x16x32_bf16(ah[i], bl[j], acc[i][j], 0,0,0);
        acc[i][j] = __builtin_amdgcn_mfma_f32_16x16x32_bf16(al[i], bh[j], acc[i][j], 0,0,0);
      }
  }

  // norms: pair-combine halves, publish to LDS
  float full = nrm + __shfl_xor(nrm, 1, 64);
  if(kh == 0) normB[r] = full;
  __syncthreads();

  // epilogue: per-row argmin of norm[s] - 2*dot; first-min tie-break via index compare
  int q = lane >> 4, c = lane & 15;
  #pragma unroll
  for(int mt=0; mt<4; mt++){
    #pragma unroll
    for(int i=0;i<4;i++){
      int t = (wave>>1)*64 + mt*16 + q*4 + i;
      float bv = BIGF; int bi = 0x7FFFFFFF;
      #pragma unroll
      for(int nt=0; nt<4; nt++){
        int sl = (wave&1)*64 + nt*16 + c;
        float sc = normB[sl] - 2.f*acc[mt][nt][i];
        int s = sbase + sl;
        if(sc < bv || (sc == bv && s < bi)){ bv = sc; bi = s; }
      }
      #pragma unroll
      for(int off=1; off<16; off<<=1){
        float ov = __shfl_xor(bv, off, 64);
        int   oi = __shfl_xor(bi, off, 64);
        if(ov < bv || (ov == bv && oi < bi)){ bv = ov; bi = oi; }
      }
      if(c == 0){
        pval[(size_t)(b*T_ + t)*PVW_ + ch*2 + (wave&1)] = bv;
        pidx[(size_t)(b*T_ + t)*PVW_ + ch*2 + (wave&1)] = bi;
      }
    }
  }
}

// ---------------- K5: final reduce + onehot + 0.5 * tm . proto^T ----------------
// grid B*16 (8 t per block), 256 thr: thread = (t_local = tid>>5, n = tid&31)
__global__ __launch_bounds__(256) void k_final(const float* __restrict__ tm, const float* __restrict__ pval,
        const int* __restrict__ pidx, const int* __restrict__ labels, const float* __restrict__ proto,
        float* __restrict__ out0){
  __shared__ int lbl_t[8];
  int b = blockIdx.x >> 4, tg = blockIdx.x & 15;
  int tid = threadIdx.x;
  if(tid < 8){
    int t = tg*8 + tid;
    float bv = BIGF; int bi = 0;
    #pragma unroll
    for(int c=0;c<PVW_;c++){
      float v = pval[(size_t)(b*T_ + t)*PVW_ + c];
      if(v < bv){ bv = v; bi = pidx[(size_t)(b*T_ + t)*PVW_ + c]; }
    }
    lbl_t[tid] = labels[b*S_ + bi];
  }
  __syncthreads();
  int tl = tid >> 5, n = tid & 31;
  int t = tg*8 + tl;
  const float4* tm4 = (const float4*)tm + (size_t)(b*T_ + t)*(D_/4);
  const float4* pr4 = (const float4*)proto + (size_t)(b*NT_ + n)*(D_/4);
  float acc = 0.f;
  #pragma unroll 8
  for(int d4=0; d4<D_/4; d4++){
    float4 x = tm4[d4], y = pr4[d4];
    acc += x.x*y.x + x.y*y.y + x.z*y.z + x.w*y.w;
  }
  out0[(size_t)(b*T_ + t)*NT_ + n] = 0.5f*acc + ((lbl_t[tl]==n) ? 1.f : 0.f);
}

extern "C" void kernel_launch(void* const* d_in, const int* in_sizes, int n_in,
                              void* d_out, int out_size, void* d_ws, size_t ws_size,
                              hipStream_t stream){
  const float* tr  = (const float*)d_in[0];   // test_reps    (B,K,T,D)
  const float* sup = (const float*)d_in[1];   // support_reps (B,K,L,D)
  const float* tgt = (const float*)d_in[4];   // support_targets (B,K,L,NT)
  float* out0  = (float*)d_out;                       // (B,T,NT)
  float* proto = out0 + (size_t)B_*T_*NT_;            // (B,NT,D)

  float* tm    = (float*)d_ws;                        // B*T*D
  int*   labels= (int*)(tm + (size_t)B_*T_*D_);       // B*S
  float* pval  = (float*)(labels + (size_t)B_*S_);    // B*T*PVW_
  int*   pidx  = (int*)(pval + (size_t)B_*T_*PVW_);   // B*T*PVW_
  int*   cnt   = (int*)(pidx + (size_t)B_*T_*PVW_);   // B*NT

  k_zero<<<(B_*NT_*D_/4)/256, 256, 0, stream>>>(proto, cnt);
  k_mean<<<(B_*T_*(D_/4))/256, 256, 0, stream>>>(tr, tm);
  k_label<<<(B_*S_)/256, 256, 0, stream>>>(tgt, labels, cnt);
  k_proto_partial<<<B_*PSC_*PDC_, 256, 0, stream>>>(sup, labels, proto);
  k_proto_div<<<(B_*NT_*D_/4)/256, 256, 0, stream>>>(proto, cnt);
  k_gemm_argmin<<<B_*NCH_, 256, 0, stream>>>(tm, sup, pval, pidx);
  k_final<<<B_*16, 256, 0, stream>>>(tm, pval, pidx, labels, proto, out0);
}

// Round 3
// 519.853 us; speedup vs baseline: 1.3853x; 1.3189x over previous
//
#include <hip/hip_runtime.h>

#define B_ 32
#define K_ 10
#define T_ 128
#define L_ 128
#define D_ 1024
#define NT_ 32
#define S_ (K_*L_)     // 1280
#define NCH_ 10        // S chunks of 128 (gemm)
#define SCH_ 128
#define PVW_ (NCH_*2)  // pval entries per row (chunk x n-half)
#define BKT_ 256       // bucket capacity per (b,n); mean count=40, 256 is >30 sigma
#define BIGF 1e30f

typedef __attribute__((ext_vector_type(8))) short short8;
typedef __attribute__((ext_vector_type(4))) float f32x4;

__device__ __forceinline__ unsigned short bf16rn(float f){
  unsigned int u = __float_as_uint(f);
  u = (u + 0x7FFFu + ((u >> 16) & 1u)) >> 16;
  return (unsigned short)u;
}
__device__ __forceinline__ float bf2f(unsigned short h){
  return __uint_as_float(((unsigned int)h) << 16);
}
__device__ __forceinline__ void f4add(float4& a, const float4& v){
  a.x+=v.x; a.y+=v.y; a.z+=v.z; a.w+=v.w;
}

// ---------------- K0: zero per-(b,n) counts ----------------
__global__ __launch_bounds__(256) void k_zero_cnt(int* __restrict__ cnt){
  ((int4*)cnt)[threadIdx.x] = make_int4(0,0,0,0);   // B*NT = 1024 ints
}

// ---------------- K1: test_mean = mean over K ----------------
__global__ __launch_bounds__(256) void k_mean(const float* __restrict__ tr, float* __restrict__ tm){
  int idx = blockIdx.x*256 + threadIdx.x;       // over B*T*(D/4)
  int d4 = idx & 255;
  int t  = (idx >> 8) & 127;
  int b  = idx >> 15;
  const float4* p = (const float4*)tr;
  float4 a = make_float4(0.f,0.f,0.f,0.f);
  #pragma unroll
  for(int k=0;k<K_;k++){
    float4 v = p[((size_t)(b*K_+k)*T_ + t)*(D_/4) + d4];
    a.x+=v.x; a.y+=v.y; a.z+=v.z; a.w+=v.w;
  }
  const float sc = 1.f/(float)K_;
  a.x*=sc; a.y*=sc; a.z*=sc; a.w*=sc;
  ((float4*)tm)[((size_t)b*T_ + t)*(D_/4) + d4] = a;
}

// ---------------- K2: labels from one-hot targets + bucket build ----------------
__global__ __launch_bounds__(256) void k_label(const float* __restrict__ tgt, int* __restrict__ labels,
                                               int* __restrict__ cnt, int* __restrict__ bucket){
  int r = blockIdx.x*256 + threadIdx.x;         // r < B*S
  const float4* p = (const float4*)tgt + (size_t)r*8;
  int lbl = 0;
  #pragma unroll
  for(int j=0;j<8;j++){
    float4 v = p[j];
    if(v.x>0.5f) lbl=j*4+0;
    if(v.y>0.5f) lbl=j*4+1;
    if(v.z>0.5f) lbl=j*4+2;
    if(v.w>0.5f) lbl=j*4+3;
  }
  labels[r] = lbl;
  int b = r / S_, s = r - b*S_;
  int cell = b*NT_ + lbl;
  int pos = atomicAdd(&cnt[cell], 1);
  if(pos < BKT_) bucket[cell*BKT_ + pos] = s;
}

// ---------------- K3: prototype gather (streaming, register accumulate) ----------------
// grid B*NT = 1024 blocks, 256 thr. Block = (b, tag n). thread owns one float4 column of D.
// Rows of this tag streamed coalesced (wave reads 1KB consecutive per row); no atomics.
__global__ __launch_bounds__(256) void k_proto_gather(const float* __restrict__ sup,
        const int* __restrict__ bucket, const int* __restrict__ cnt, float* __restrict__ proto){
  __shared__ int rows[BKT_];
  int b = blockIdx.x >> 5, n = blockIdx.x & 31;
  int tid = threadIdx.x;
  int cell = b*NT_ + n;
  int c = cnt[cell];
  int cc = c < BKT_ ? c : BKT_;
  for(int i=tid;i<cc;i+=256) rows[i] = bucket[cell*BKT_ + i];
  __syncthreads();

  const float* base = sup + (size_t)b*S_*D_ + tid*4;
  float4 a0 = make_float4(0,0,0,0), a1 = a0, a2 = a0, a3 = a0;
  int i = 0;
  for(; i+8 <= cc; i += 8){
    float4 v0 = *(const float4*)(base + (size_t)rows[i+0]*D_);
    float4 v1 = *(const float4*)(base + (size_t)rows[i+1]*D_);
    float4 v2 = *(const float4*)(base + (size_t)rows[i+2]*D_);
    float4 v3 = *(const float4*)(base + (size_t)rows[i+3]*D_);
    float4 v4 = *(const float4*)(base + (size_t)rows[i+4]*D_);
    float4 v5 = *(const float4*)(base + (size_t)rows[i+5]*D_);
    float4 v6 = *(const float4*)(base + (size_t)rows[i+6]*D_);
    float4 v7 = *(const float4*)(base + (size_t)rows[i+7]*D_);
    f4add(a0, v0); f4add(a1, v1); f4add(a2, v2); f4add(a3, v3);
    f4add(a0, v4); f4add(a1, v5); f4add(a2, v6); f4add(a3, v7);
  }
  for(; i < cc; i++){
    float4 v = *(const float4*)(base + (size_t)rows[i]*D_);
    f4add(a0, v);
  }
  f4add(a0, a1); f4add(a2, a3); f4add(a0, a2);
  float inv = 1.f / ((float)c + 1e-4f);
  a0.x*=inv; a0.y*=inv; a0.z*=inv; a0.w*=inv;
  ((float4*)proto)[(size_t)cell*(D_/4) + tid] = a0;
}

// ---------------- K4: split-bf16 MFMA GEMM (-2*t.s + ||s||^2) + per-chunk argmin ----------------
// grid b*NCH_; 256 thr = 4 waves in 2x2; block tile 128(T) x 128(S), BK=32 fp32 staged as bf16 hi/lo.
// LDS frag-major: seg(mt,p) = 1KB holding the exact 64-lane x 16B fragment -> conflict-free b128.
__global__ __launch_bounds__(256) void k_gemm_argmin(const float* __restrict__ tm, const float* __restrict__ sup,
        float* __restrict__ pval, int* __restrict__ pidx){
  __shared__ __align__(16) short ldsA[16*512];   // 8 mt x 2 planes x 512 shorts (1KB segs)
  __shared__ __align__(16) short ldsB[16*512];
  __shared__ float normB[128];

  int b = blockIdx.x / NCH_;
  int ch = blockIdx.x % NCH_;
  int sbase = ch * SCH_;
  int tid = threadIdx.x;
  int wave = tid >> 6, lane = tid & 63;
  int r = tid >> 1, kh = tid & 1;               // staging: row 0..127, k-half
  int mbase = (wave >> 1)*4;                    // wave's first mtile
  int nbase = (wave & 1)*4;                     // wave's first ntile

  const float* pa_base = tm  + ((size_t)b*T_ + r)*D_ + kh*16;
  const float* pb_base = sup + ((size_t)b*S_ + sbase + r)*D_ + kh*16;

  f32x4 acc[4][4];
  #pragma unroll
  for(int i=0;i<4;i++)
    #pragma unroll
    for(int j=0;j<4;j++) acc[i][j] = (f32x4){0.f,0.f,0.f,0.f};

  float nrm = 0.f;
  float4 a_reg[4], b_reg[4];
  #pragma unroll
  for(int it=0;it<4;it++){
    a_reg[it] = *(const float4*)(pa_base + it*4);
    b_reg[it] = *(const float4*)(pb_base + it*4);
  }

  for(int st=0; st<32; st++){
    __syncthreads();                            // LDS free (prev compute done)
    // convert + store hi/lo planes, accumulate sup row sumsq from fp32
    #pragma unroll
    for(int it=0;it<4;it++){
      float4 v = a_reg[it];
      int basei = ((r>>4)*2)*512 + ((kh*2+(it>>1))*16 + (r&15))*8 + (it&1)*4;
      unsigned short hx=bf16rn(v.x), hy=bf16rn(v.y), hz=bf16rn(v.z), hw=bf16rn(v.w);
      *(uint2*)&ldsA[basei] = make_uint2((unsigned)hx|((unsigned)hy<<16),(unsigned)hz|((unsigned)hw<<16));
      unsigned short lx=bf16rn(v.x-bf2f(hx)), ly=bf16rn(v.y-bf2f(hy)), lz=bf16rn(v.z-bf2f(hz)), lw=bf16rn(v.w-bf2f(hw));
      *(uint2*)&ldsA[basei + 512] = make_uint2((unsigned)lx|((unsigned)ly<<16),(unsigned)lz|((unsigned)lw<<16));

      float4 w = b_reg[it];
      nrm += w.x*w.x + w.y*w.y + w.z*w.z + w.w*w.w;
      unsigned short qx=bf16rn(w.x), qy=bf16rn(w.y), qz=bf16rn(w.z), qw=bf16rn(w.w);
      *(uint2*)&ldsB[basei] = make_uint2((unsigned)qx|((unsigned)qy<<16),(unsigned)qz|((unsigned)qw<<16));
      unsigned short ux=bf16rn(w.x-bf2f(qx)), uy=bf16rn(w.y-bf2f(qy)), uz=bf16rn(w.z-bf2f(qz)), uw=bf16rn(w.w-bf2f(qw));
      *(uint2*)&ldsB[basei + 512] = make_uint2((unsigned)ux|((unsigned)uy<<16),(unsigned)uz|((unsigned)uw<<16));
    }
    __syncthreads();
    if(st < 31){
      #pragma unroll
      for(int it=0;it<4;it++){
        a_reg[it] = *(const float4*)(pa_base + (st+1)*32 + it*4);
        b_reg[it] = *(const float4*)(pb_base + (st+1)*32 + it*4);
      }
    }
    short8 ah[4], al[4], bh[4], bl[4];
    #pragma unroll
    for(int i=0;i<4;i++){
      ah[i] = *(const short8*)&ldsA[((mbase+i)*2+0)*512 + lane*8];
      al[i] = *(const short8*)&ldsA[((mbase+i)*2+1)*512 + lane*8];
      bh[i] = *(const short8*)&ldsB[((nbase+i)*2+0)*512 + lane*8];
      bl[i] = *(const short8*)&ldsB[((nbase+i)*2+1)*512 + lane*8];
    }
    #pragma unroll
    for(int i=0;i<4;i++)
      #pragma unroll
      for(int j=0;j<4;j++){
        acc[i][j] = __builtin_amdgcn_mfma_f32_16x16x32_bf16(ah[i], bh[j], acc[i][j], 0,0,0);
        acc[i][j] = __builtin_amdgcn_mfma_f32_16x16x32_bf16(ah[i], bl[j], acc[i][j], 0,0,0);
        acc[i][j] = __builtin_amdgcn_mfma_f32_16x16x32_bf16(al[i], bh[j], acc[i][j], 0,0,0);
      }
  }

  // norms: pair-combine halves, publish to LDS
  float full = nrm + __shfl_xor(nrm, 1, 64);
  if(kh == 0) normB[r] = full;
  __syncthreads();

  // epilogue: per-row argmin of norm[s] - 2*dot; first-min tie-break via index compare
  int q = lane >> 4, c = lane & 15;
  #pragma unroll
  for(int mt=0; mt<4; mt++){
    #pragma unroll
    for(int i=0;i<4;i++){
      int t = (wave>>1)*64 + mt*16 + q*4 + i;
      float bv = BIGF; int bi = 0x7FFFFFFF;
      #pragma unroll
      for(int nt=0; nt<4; nt++){
        int sl = (wave&1)*64 + nt*16 + c;
        float sc = normB[sl] - 2.f*acc[mt][nt][i];
        int s = sbase + sl;
        if(sc < bv || (sc == bv && s < bi)){ bv = sc; bi = s; }
      }
      #pragma unroll
      for(int off=1; off<16; off<<=1){
        float ov = __shfl_xor(bv, off, 64);
        int   oi = __shfl_xor(bi, off, 64);
        if(ov < bv || (ov == bv && oi < bi)){ bv = ov; bi = oi; }
      }
      if(c == 0){
        pval[(size_t)(b*T_ + t)*PVW_ + ch*2 + (wave&1)] = bv;
        pidx[(size_t)(b*T_ + t)*PVW_ + ch*2 + (wave&1)] = bi;
      }
    }
  }
}

// ---------------- K5: final reduce + onehot + 0.5 * tm . proto^T ----------------
// grid B*16 (8 t per block), 256 thr: thread = (t_local = tid>>5, n = tid&31)
__global__ __launch_bounds__(256) void k_final(const float* __restrict__ tm, const float* __restrict__ pval,
        const int* __restrict__ pidx, const int* __restrict__ labels, const float* __restrict__ proto,
        float* __restrict__ out0){
  __shared__ int lbl_t[8];
  int b = blockIdx.x >> 4, tg = blockIdx.x & 15;
  int tid = threadIdx.x;
  if(tid < 8){
    int t = tg*8 + tid;
    float bv = BIGF; int bi = 0;
    #pragma unroll
    for(int c=0;c<PVW_;c++){
      float v = pval[(size_t)(b*T_ + t)*PVW_ + c];
      if(v < bv){ bv = v; bi = pidx[(size_t)(b*T_ + t)*PVW_ + c]; }
    }
    lbl_t[tid] = labels[b*S_ + bi];
  }
  __syncthreads();
  int tl = tid >> 5, n = tid & 31;
  int t = tg*8 + tl;
  const float4* tm4 = (const float4*)tm + (size_t)(b*T_ + t)*(D_/4);
  const float4* pr4 = (const float4*)proto + (size_t)(b*NT_ + n)*(D_/4);
  float acc = 0.f;
  #pragma unroll 8
  for(int d4=0; d4<D_/4; d4++){
    float4 x = tm4[d4], y = pr4[d4];
    acc += x.x*y.x + x.y*y.y + x.z*y.z + x.w*y.w;
  }
  out0[(size_t)(b*T_ + t)*NT_ + n] = 0.5f*acc + ((lbl_t[tl]==n) ? 1.f : 0.f);
}

extern "C" void kernel_launch(void* const* d_in, const int* in_sizes, int n_in,
                              void* d_out, int out_size, void* d_ws, size_t ws_size,
                              hipStream_t stream){
  const float* tr  = (const float*)d_in[0];   // test_reps    (B,K,T,D)
  const float* sup = (const float*)d_in[1];   // support_reps (B,K,L,D)
  const float* tgt = (const float*)d_in[4];   // support_targets (B,K,L,NT)
  float* out0  = (float*)d_out;                       // (B,T,NT)
  float* proto = out0 + (size_t)B_*T_*NT_;            // (B,NT,D)

  float* tm    = (float*)d_ws;                        // B*T*D
  int*   labels= (int*)(tm + (size_t)B_*T_*D_);       // B*S
  float* pval  = (float*)(labels + (size_t)B_*S_);    // B*T*PVW_
  int*   pidx  = (int*)(pval + (size_t)B_*T_*PVW_);   // B*T*PVW_
  int*   cnt   = (int*)(pidx + (size_t)B_*T_*PVW_);   // B*NT
  int*   bucket= cnt + (size_t)B_*NT_;                // B*NT*BKT_

  k_zero_cnt<<<1, 256, 0, stream>>>(cnt);
  k_mean<<<(B_*T_*(D_/4))/256, 256, 0, stream>>>(tr, tm);
  k_label<<<(B_*S_)/256, 256, 0, stream>>>(tgt, labels, cnt, bucket);
  k_proto_gather<<<B_*NT_, 256, 0, stream>>>(sup, bucket, cnt, proto);
  k_gemm_argmin<<<B_*NCH_, 256, 0, stream>>>(tm, sup, pval, pidx);
  k_final<<<B_*16, 256, 0, stream>>>(tm, pval, pidx, labels, proto, out0);
}